// Round 3
// baseline (731.743 us; speedup 1.0000x reference)
//
#include <hip/hip_runtime.h>
#include <hip/hip_bf16.h>
#include <stdint.h>

typedef __hip_bfloat16 bf16;
typedef __attribute__((ext_vector_type(4))) float f32x4;
typedef __attribute__((ext_vector_type(8))) short short8;

#define DEVI static __device__ __forceinline__
#define SM_SCALE 0.08838834764831845f

// async global->LDS, 16B per lane. LDS dest must be wave-uniform base; HW adds lane*16.
DEVI void gload_lds16(const bf16* g, bf16* l) {
  __builtin_amdgcn_global_load_lds(
      (const __attribute__((address_space(1))) unsigned int*)g,
      (__attribute__((address_space(3))) unsigned int*)l, 16, 0, 0);
}

// ---------------- fp32 -> bf16 elementwise convert (8 elems/thread) ----------------
__global__ __launch_bounds__(256) void cvt_f32_bf16(const float* __restrict__ in,
                                                    bf16* __restrict__ out, int n8) {
  int i = blockIdx.x * blockDim.x + threadIdx.x;
  if (i >= n8) return;
  const float4 a = *(const float4*)(in + (size_t)i * 8);
  const float4 b = *(const float4*)(in + (size_t)i * 8 + 4);
  bf16 t[8];
  t[0] = __float2bfloat16(a.x); t[1] = __float2bfloat16(a.y);
  t[2] = __float2bfloat16(a.z); t[3] = __float2bfloat16(a.w);
  t[4] = __float2bfloat16(b.x); t[5] = __float2bfloat16(b.y);
  t[6] = __float2bfloat16(b.z); t[7] = __float2bfloat16(b.w);
  *(short8*)(out + (size_t)i * 8) = *(const short8*)t;
}

// ---- fp32 [R][C] -> bf16 [C][R] transpose+convert; scales output-rows < scale_lt ----
__global__ __launch_bounds__(256) void transpose_cvt(const float* __restrict__ in,
                                                     bf16* __restrict__ out,
                                                     int R, int C, int scale_lt,
                                                     float scale) {
  __shared__ bf16 tile[64][72];
  const int c0 = blockIdx.x * 64, r0 = blockIdx.y * 64;
  const int t = threadIdx.x;
#pragma unroll
  for (int i = 0; i < 4; i++) {
    int idx = (i * 256 + t) * 4;
    int r = idx >> 6, c = idx & 63;
    float4 v = *(const float4*)&in[(size_t)(r0 + r) * C + c0 + c];
    float s0 = (c0 + c + 0 < scale_lt) ? scale : 1.f;
    float s1 = (c0 + c + 1 < scale_lt) ? scale : 1.f;
    float s2 = (c0 + c + 2 < scale_lt) ? scale : 1.f;
    float s3 = (c0 + c + 3 < scale_lt) ? scale : 1.f;
    tile[c + 0][r] = __float2bfloat16(v.x * s0);
    tile[c + 1][r] = __float2bfloat16(v.y * s1);
    tile[c + 2][r] = __float2bfloat16(v.z * s2);
    tile[c + 3][r] = __float2bfloat16(v.w * s3);
  }
  __syncthreads();
#pragma unroll
  for (int i = 0; i < 2; i++) {
    int idx = (i * 256 + t) * 8;
    int c = idx >> 6, r = idx & 63;
    *(short8*)&out[(size_t)(c0 + c) * R + r0 + r] = *(const short8*)&tile[c][r];
  }
}

// ------- extract V head-blocks from qkv and transpose: vt[bh][d=128][s=2048] -------
__global__ __launch_bounds__(256) void build_vt(const bf16* __restrict__ qkv,
                                                bf16* __restrict__ vt) {
  __shared__ bf16 tile[64][72];
  const int bh = blockIdx.z, b = bh >> 4, h = bh & 15;
  const bf16* src = qkv + (size_t)b * 2048 * 6144 + 4096 + (size_t)h * 128;
  bf16* dst = vt + (size_t)bh * 128 * 2048;
  const int s0 = blockIdx.y * 64, d0 = blockIdx.x * 64;
  const int t = threadIdx.x;
#pragma unroll
  for (int i = 0; i < 2; i++) {
    int idx = (i * 256 + t) * 8;
    int r = idx >> 6, c = idx & 63;
    short8 v = *(const short8*)&src[(size_t)(s0 + r) * 6144 + d0 + c];
    bf16* vv = (bf16*)&v;
#pragma unroll
    for (int j = 0; j < 8; j++) tile[c + j][r] = vv[j];
  }
  __syncthreads();
#pragma unroll
  for (int i = 0; i < 2; i++) {
    int idx = (i * 256 + t) * 8;
    int r = idx >> 6, c = idx & 63;
    *(short8*)&dst[(size_t)(d0 + r) * 2048 + s0 + c] = *(const short8*)&tile[r][c];
  }
}

// ---------------- m97-structure GEMM: C[M][N] = A[M][K] * Bt[N][K]^T + bias ----------------
// bias cols < bias_lt get multiplied by bscale (folds softmax scale into Q bias).
template <int OUT_BF16>
__global__ __launch_bounds__(256, 2) void gemm_bt(const bf16* __restrict__ A,
                                                  const bf16* __restrict__ Bt,
                                                  const float* __restrict__ bias,
                                                  void* __restrict__ C,
                                                  const int M, const int N, const int K,
                                                  const int bias_lt, const float bscale) {
  __shared__ bf16 As[128 * 32];
  __shared__ bf16 Bs[128 * 32];
  const int t = threadIdx.x, lane = t & 63, w = t >> 6;
  const int wr = w >> 1, wc = w & 1;
  const int lrow = lane >> 4, lcol = lane & 15;

  int bid = blockIdx.y * gridDim.x + blockIdx.x;
  const int nwg = gridDim.x * gridDim.y;
  bid = (bid & 7) * (nwg >> 3) + (bid >> 3);
  const int bx = bid % gridDim.x, by = bid / gridDim.x;
  const int m0 = by * 128, n0 = bx * 128;

  f32x4 acc[4][4];
#pragma unroll
  for (int i = 0; i < 4; i++)
#pragma unroll
    for (int j = 0; j < 4; j++) acc[i][j] = (f32x4){0.f, 0.f, 0.f, 0.f};

  for (int k0 = 0; k0 < K; k0 += 32) {
    __syncthreads();
#pragma unroll
    for (int i = 0; i < 2; i++) {
      const int o = i * 256 + t;
      gload_lds16(&A[(size_t)(m0 + (o >> 2)) * K + k0 + ((o & 3) << 3)],
                  &As[(i * 256 + w * 64) * 8]);
      gload_lds16(&Bt[(size_t)(n0 + (o >> 2)) * K + k0 + ((o & 3) << 3)],
                  &Bs[(i * 256 + w * 64) * 8]);
    }
    asm volatile("s_waitcnt vmcnt(0)" ::: "memory");
    __syncthreads();
    short8 af[4], bfr[4];
#pragma unroll
    for (int m = 0; m < 4; m++)
      af[m] = *(const short8*)&As[(wr * 64 + m * 16 + lcol) * 32 + lrow * 8];
#pragma unroll
    for (int n = 0; n < 4; n++)
      bfr[n] = *(const short8*)&Bs[(wc * 64 + n * 16 + lcol) * 32 + lrow * 8];
#pragma unroll
    for (int m = 0; m < 4; m++)
#pragma unroll
      for (int n = 0; n < 4; n++)
        acc[m][n] = __builtin_amdgcn_mfma_f32_16x16x32_bf16(af[m], bfr[n], acc[m][n], 0, 0, 0);
  }

  float bs[4];
#pragma unroll
  for (int n = 0; n < 4; n++) {
    const int col = n0 + wc * 64 + n * 16 + lcol;
    bs[n] = bias[col] * ((col < bias_lt) ? bscale : 1.f);
  }
#pragma unroll
  for (int m = 0; m < 4; m++) {
#pragma unroll
    for (int n = 0; n < 4; n++) {
      const int row = m0 + wr * 64 + m * 16 + lrow * 4;
      const int col = n0 + wc * 64 + n * 16 + lcol;
#pragma unroll
      for (int r = 0; r < 4; r++) {
        float v = acc[m][n][r] + bs[n];
        if (OUT_BF16)
          ((bf16*)C)[(size_t)(row + r) * N + col] = __float2bfloat16(v);
        else
          ((float*)C)[(size_t)(row + r) * N + col] = v;
      }
    }
  }
}

// ---------------- flash causal attention, work-balanced pair version ----------------
// Block handles q-tiles i and 31-i (64 rows each, 4 waves x 16 rows) with a SHARED
// k-sweep: each K/V tile staged once, consumed by both q-tiles -> every block does
// exactly 33 q*k tile-computes (perfect balance). Q pre-scaled by SM_SCALE upstream.
__global__ __launch_bounds__(256, 3) void flash_attn(const bf16* __restrict__ qkv,
                                                     const bf16* __restrict__ vt,
                                                     bf16* __restrict__ attn) {
  constexpr int S = 2048, TH = 6144, HH = 2048, D = 128;
  __shared__ bf16 Kl[64][140];     // row stride 280B == 6 words mod 32
  __shared__ bf16 Vl[128][76];     // row stride 152B == 6 words mod 32
  __shared__ bf16 Pl[4][16][76];   // scatter: lrow offset 24 words mod 32 -> 2-way
  const int t = threadIdx.x, lane = t & 63, w = t >> 6;
  const int lrow = lane >> 4, lcol = lane & 15;

  // XCD swizzle: 64 consecutive-swz blocks = 4 bh -> ~4MB K/V footprint per XCD L2
  int id = blockIdx.y * gridDim.x + blockIdx.x;  // 512 blocks
  id = (id & 7) * 64 + (id >> 3);
  const int i = id & 15, bh = id >> 4;
  const int b = bh >> 4, h = bh & 15;
  const int q0a = i * 64, q0b = (31 - i) * 64;

  const bf16* Qp = qkv + (size_t)b * S * TH + (size_t)h * D;
  const bf16* Kp = Qp + 2048;
  const bf16* Vp = vt + (size_t)bh * D * S;

  short8 aqA[4], aqB[4];
#pragma unroll
  for (int kc = 0; kc < 4; kc++) {
    aqA[kc] = *(const short8*)&Qp[(size_t)(q0a + w * 16 + lcol) * TH + kc * 32 + lrow * 8];
    aqB[kc] = *(const short8*)&Qp[(size_t)(q0b + w * 16 + lcol) * TH + kc * 32 + lrow * 8];
  }

  f32x4 oA[8], oB[8];
  float mxA[4], lsA[4], mxB[4], lsB[4];
#pragma unroll
  for (int nd = 0; nd < 8; nd++) { oA[nd] = (f32x4){0.f,0.f,0.f,0.f}; oB[nd] = (f32x4){0.f,0.f,0.f,0.f}; }
#pragma unroll
  for (int r = 0; r < 4; r++) { mxA[r] = -1e30f; lsA[r] = 0.f; mxB[r] = -1e30f; lsB[r] = 0.f; }

  auto step = [&](int q0, const short8* aq, f32x4* o, float* mx, float* ls, int k0) {
    f32x4 s[4];
#pragma unroll
    for (int n = 0; n < 4; n++) s[n] = (f32x4){0.f, 0.f, 0.f, 0.f};
#pragma unroll
    for (int n = 0; n < 4; n++) {
      short8 bk[4];
#pragma unroll
      for (int kc = 0; kc < 4; kc++)
        bk[kc] = *(const short8*)&Kl[n * 16 + lcol][kc * 32 + lrow * 8];
#pragma unroll
      for (int kc = 0; kc < 4; kc++)
        s[n] = __builtin_amdgcn_mfma_f32_16x16x32_bf16(aq[kc], bk[kc], s[n], 0, 0, 0);
    }
    if (k0 + 63 > q0 + w * 16) {  // only the diagonal tile needs masking
#pragma unroll
      for (int n = 0; n < 4; n++)
#pragma unroll
        for (int r = 0; r < 4; r++) {
          int qg = q0 + w * 16 + lrow * 4 + r;
          int kg = k0 + n * 16 + lcol;
          if (kg > qg) s[n][r] = -1e30f;
        }
    }
#pragma unroll
    for (int r = 0; r < 4; r++) {
      float rm = fmaxf(fmaxf(s[0][r], s[1][r]), fmaxf(s[2][r], s[3][r]));
      rm = fmaxf(rm, __shfl_xor(rm, 1));
      rm = fmaxf(rm, __shfl_xor(rm, 2));
      rm = fmaxf(rm, __shfl_xor(rm, 4));
      rm = fmaxf(rm, __shfl_xor(rm, 8));
      const float mn = fmaxf(mx[r], rm);
      const float fac = __expf(mx[r] - mn);
      mx[r] = mn;
      float rs = 0.f;
#pragma unroll
      for (int n = 0; n < 4; n++) {
        float p = __expf(s[n][r] - mn);
        s[n][r] = p;
        rs += p;
      }
      rs += __shfl_xor(rs, 1);
      rs += __shfl_xor(rs, 2);
      rs += __shfl_xor(rs, 4);
      rs += __shfl_xor(rs, 8);
      ls[r] = ls[r] * fac + rs;
#pragma unroll
      for (int nd = 0; nd < 8; nd++) o[nd][r] *= fac;
    }
    // P -> per-wave LDS (C-layout scatter), reload as A-fragments
#pragma unroll
    for (int n = 0; n < 4; n++)
#pragma unroll
      for (int r = 0; r < 4; r++)
        Pl[w][lrow * 4 + r][n * 16 + lcol] = __float2bfloat16(s[n][r]);
    short8 ap[2];
#pragma unroll
    for (int kc = 0; kc < 2; kc++)
      ap[kc] = *(const short8*)&Pl[w][lcol][kc * 32 + lrow * 8];
#pragma unroll
    for (int nd = 0; nd < 8; nd++) {
      short8 bv[2];
#pragma unroll
      for (int kc = 0; kc < 2; kc++)
        bv[kc] = *(const short8*)&Vl[nd * 16 + lcol][kc * 32 + lrow * 8];
#pragma unroll
      for (int kc = 0; kc < 2; kc++)
        o[nd] = __builtin_amdgcn_mfma_f32_16x16x32_bf16(ap[kc], bv[kc], o[nd], 0, 0, 0);
    }
  };

  const int nkt = 32 - i;  // k-tiles 0 .. 31-i  (tile B's full causal range)
  for (int kt = 0; kt < nkt; ++kt) {
    const int k0 = kt * 64;
    __syncthreads();
#pragma unroll
    for (int i2 = 0; i2 < 4; i2++) {  // stage K: 64 x 128
      int idx = (i2 * 256 + t) * 8;
      int r = idx >> 7, c = idx & 127;
      *(short8*)&Kl[r][c] = *(const short8*)&Kp[(size_t)(k0 + r) * TH + c];
    }
#pragma unroll
    for (int i2 = 0; i2 < 4; i2++) {  // stage V^T: 128 x 64
      int idx = (i2 * 256 + t) * 8;
      int r = idx >> 6, c = idx & 63;
      *(short8*)&Vl[r][c] = *(const short8*)&Vp[(size_t)r * S + k0 + c];
    }
    __syncthreads();
    step(q0b, aqB, oB, mxB, lsB, k0);      // long tile: every k-tile
    if (kt <= i) step(q0a, aqA, oA, mxA, lsA, k0);  // short tile: k <= diag
  }

#pragma unroll
  for (int nd = 0; nd < 8; nd++)
#pragma unroll
    for (int r = 0; r < 4; r++) {
      attn[(size_t)(b * S + q0a + w * 16 + lrow * 4 + r) * HH + h * D + nd * 16 + lcol] =
          __float2bfloat16(oA[nd][r] / lsA[r]);
      attn[(size_t)(b * S + q0b + w * 16 + lrow * 4 + r) * HH + h * D + nd * 16 + lcol] =
          __float2bfloat16(oB[nd][r] / lsB[r]);
    }
}

extern "C" void kernel_launch(void* const* d_in, const int* in_sizes, int n_in,
                              void* d_out, int out_size, void* d_ws, size_t ws_size,
                              hipStream_t stream) {
  const float* hidden = (const float*)d_in[0];  // [2,2048,2048]
  const float* w_attn = (const float*)d_in[1];  // [2048,6144]
  const float* b_attn = (const float*)d_in[2];  // [6144]
  const float* w_proj = (const float*)d_in[3];  // [2048,2048]
  const float* b_proj = (const float*)d_in[4];  // [2048]

  char* ws = (char*)d_ws;
  bf16* hb    = (bf16*)(ws);                 // [4096][2048]        16 MB
  bf16* wab_t = (bf16*)(ws + 16777216ull);   // [6144][2048]        24 MB
  bf16* wpb_t = (bf16*)(ws + 41943040ull);   // [2048][2048]         8 MB
  bf16* qkv   = (bf16*)(ws + 50331648ull);   // [4096][6144]        48 MB
  bf16* vt    = (bf16*)(ws + 100663296ull);  // [32][128][2048]     16 MB
  bf16* attn  = (bf16*)(ws + 117440512ull);  // [4096][2048]        16 MB  (total 128 MB)

  cvt_f32_bf16<<<4096, 256, 0, stream>>>(hidden, hb, 4096 * 2048 / 8);
  // fold softmax scale into W_q (cols < 2048 of w_attn)
  transpose_cvt<<<dim3(96, 32), 256, 0, stream>>>(w_attn, wab_t, 2048, 6144, 2048, SM_SCALE);
  transpose_cvt<<<dim3(32, 32), 256, 0, stream>>>(w_proj, wpb_t, 2048, 2048, 0, 1.f);
  gemm_bt<1><<<dim3(48, 32), 256, 0, stream>>>(hb, wab_t, b_attn, (void*)qkv, 4096, 6144, 2048,
                                               2048, SM_SCALE);
  build_vt<<<dim3(2, 32, 32), 256, 0, stream>>>(qkv, vt);
  flash_attn<<<dim3(16, 32), 256, 0, stream>>>(qkv, vt, attn);
  gemm_bt<0><<<dim3(16, 32), 256, 0, stream>>>(attn, wpb_t, b_proj, d_out, 4096, 2048, 2048,
                                               0, 1.f);
}

// Round 4
// 477.941 us; speedup vs baseline: 1.5310x; 1.5310x over previous
//
#include <hip/hip_runtime.h>
#include <hip/hip_bf16.h>
#include <stdint.h>

typedef __hip_bfloat16 bf16;
typedef __attribute__((ext_vector_type(4))) float f32x4;
typedef __attribute__((ext_vector_type(8))) short short8;

#define DEVI static __device__ __forceinline__
#define SM_SCALE 0.08838834764831845f

// async global->LDS, 16B per lane. LDS dest must be wave-uniform base; HW adds lane*16.
DEVI void gload_lds16(const bf16* g, bf16* l) {
  __builtin_amdgcn_global_load_lds(
      (const __attribute__((address_space(1))) unsigned int*)g,
      (__attribute__((address_space(3))) unsigned int*)l, 16, 0, 0);
}

// ---------------- fp32 -> bf16 elementwise convert (8 elems/thread) ----------------
__global__ __launch_bounds__(256) void cvt_f32_bf16(const float* __restrict__ in,
                                                    bf16* __restrict__ out, int n8) {
  int i = blockIdx.x * blockDim.x + threadIdx.x;
  if (i >= n8) return;
  const float4 a = *(const float4*)(in + (size_t)i * 8);
  const float4 b = *(const float4*)(in + (size_t)i * 8 + 4);
  bf16 t[8];
  t[0] = __float2bfloat16(a.x); t[1] = __float2bfloat16(a.y);
  t[2] = __float2bfloat16(a.z); t[3] = __float2bfloat16(a.w);
  t[4] = __float2bfloat16(b.x); t[5] = __float2bfloat16(b.y);
  t[6] = __float2bfloat16(b.z); t[7] = __float2bfloat16(b.w);
  *(short8*)(out + (size_t)i * 8) = *(const short8*)t;
}

// ---- fp32 [R][C] -> bf16 [C][R] transpose+convert; scales output-rows < scale_lt ----
__global__ __launch_bounds__(256) void transpose_cvt(const float* __restrict__ in,
                                                     bf16* __restrict__ out,
                                                     int R, int C, int scale_lt,
                                                     float scale) {
  __shared__ bf16 tile[64][72];
  const int c0 = blockIdx.x * 64, r0 = blockIdx.y * 64;
  const int t = threadIdx.x;
#pragma unroll
  for (int i = 0; i < 4; i++) {
    int idx = (i * 256 + t) * 4;
    int r = idx >> 6, c = idx & 63;
    float4 v = *(const float4*)&in[(size_t)(r0 + r) * C + c0 + c];
    float s0 = (c0 + c + 0 < scale_lt) ? scale : 1.f;
    float s1 = (c0 + c + 1 < scale_lt) ? scale : 1.f;
    float s2 = (c0 + c + 2 < scale_lt) ? scale : 1.f;
    float s3 = (c0 + c + 3 < scale_lt) ? scale : 1.f;
    tile[c + 0][r] = __float2bfloat16(v.x * s0);
    tile[c + 1][r] = __float2bfloat16(v.y * s1);
    tile[c + 2][r] = __float2bfloat16(v.z * s2);
    tile[c + 3][r] = __float2bfloat16(v.w * s3);
  }
  __syncthreads();
#pragma unroll
  for (int i = 0; i < 2; i++) {
    int idx = (i * 256 + t) * 8;
    int c = idx >> 6, r = idx & 63;
    *(short8*)&out[(size_t)(c0 + c) * R + r0 + r] = *(const short8*)&tile[c][r];
  }
}

// ------- extract V head-blocks from qkv and transpose: vt[bh][d=128][s=2048] -------
__global__ __launch_bounds__(256) void build_vt(const bf16* __restrict__ qkv,
                                                bf16* __restrict__ vt) {
  __shared__ bf16 tile[64][72];
  const int bh = blockIdx.z, b = bh >> 4, h = bh & 15;
  const bf16* src = qkv + (size_t)b * 2048 * 6144 + 4096 + (size_t)h * 128;
  bf16* dst = vt + (size_t)bh * 128 * 2048;
  const int s0 = blockIdx.y * 64, d0 = blockIdx.x * 64;
  const int t = threadIdx.x;
#pragma unroll
  for (int i = 0; i < 2; i++) {
    int idx = (i * 256 + t) * 8;
    int r = idx >> 6, c = idx & 63;
    short8 v = *(const short8*)&src[(size_t)(s0 + r) * 6144 + d0 + c];
    bf16* vv = (bf16*)&v;
#pragma unroll
    for (int j = 0; j < 8; j++) tile[c + j][r] = vv[j];
  }
  __syncthreads();
#pragma unroll
  for (int i = 0; i < 2; i++) {
    int idx = (i * 256 + t) * 8;
    int r = idx >> 6, c = idx & 63;
    *(short8*)&dst[(size_t)(d0 + r) * 2048 + s0 + c] = *(const short8*)&tile[r][c];
  }
}

// ---------------- m97-structure GEMM: C[M][N] = A[M][K] * Bt[N][K]^T + bias ----------------
// bias cols < bias_lt get multiplied by bscale (folds softmax scale into Q bias).
template <int OUT_BF16>
__global__ __launch_bounds__(256, 2) void gemm_bt(const bf16* __restrict__ A,
                                                  const bf16* __restrict__ Bt,
                                                  const float* __restrict__ bias,
                                                  void* __restrict__ C,
                                                  const int M, const int N, const int K,
                                                  const int bias_lt, const float bscale) {
  __shared__ bf16 As[128 * 32];
  __shared__ bf16 Bs[128 * 32];
  const int t = threadIdx.x, lane = t & 63, w = t >> 6;
  const int wr = w >> 1, wc = w & 1;
  const int lrow = lane >> 4, lcol = lane & 15;

  int bid = blockIdx.y * gridDim.x + blockIdx.x;
  const int nwg = gridDim.x * gridDim.y;
  bid = (bid & 7) * (nwg >> 3) + (bid >> 3);
  const int bx = bid % gridDim.x, by = bid / gridDim.x;
  const int m0 = by * 128, n0 = bx * 128;

  f32x4 acc[4][4];
#pragma unroll
  for (int i = 0; i < 4; i++)
#pragma unroll
    for (int j = 0; j < 4; j++) acc[i][j] = (f32x4){0.f, 0.f, 0.f, 0.f};

  for (int k0 = 0; k0 < K; k0 += 32) {
    __syncthreads();
#pragma unroll
    for (int i = 0; i < 2; i++) {
      const int o = i * 256 + t;
      gload_lds16(&A[(size_t)(m0 + (o >> 2)) * K + k0 + ((o & 3) << 3)],
                  &As[(i * 256 + w * 64) * 8]);
      gload_lds16(&Bt[(size_t)(n0 + (o >> 2)) * K + k0 + ((o & 3) << 3)],
                  &Bs[(i * 256 + w * 64) * 8]);
    }
    asm volatile("s_waitcnt vmcnt(0)" ::: "memory");
    __syncthreads();
    short8 af[4], bfr[4];
#pragma unroll
    for (int m = 0; m < 4; m++)
      af[m] = *(const short8*)&As[(wr * 64 + m * 16 + lcol) * 32 + lrow * 8];
#pragma unroll
    for (int n = 0; n < 4; n++)
      bfr[n] = *(const short8*)&Bs[(wc * 64 + n * 16 + lcol) * 32 + lrow * 8];
#pragma unroll
    for (int m = 0; m < 4; m++)
#pragma unroll
      for (int n = 0; n < 4; n++)
        acc[m][n] = __builtin_amdgcn_mfma_f32_16x16x32_bf16(af[m], bfr[n], acc[m][n], 0, 0, 0);
  }

  float bs[4];
#pragma unroll
  for (int n = 0; n < 4; n++) {
    const int col = n0 + wc * 64 + n * 16 + lcol;
    bs[n] = bias[col] * ((col < bias_lt) ? bscale : 1.f);
  }
#pragma unroll
  for (int m = 0; m < 4; m++) {
#pragma unroll
    for (int n = 0; n < 4; n++) {
      const int row = m0 + wr * 64 + m * 16 + lrow * 4;
      const int col = n0 + wc * 64 + n * 16 + lcol;
#pragma unroll
      for (int r = 0; r < 4; r++) {
        float v = acc[m][n][r] + bs[n];
        if (OUT_BF16)
          ((bf16*)C)[(size_t)(row + r) * N + col] = __float2bfloat16(v);
        else
          ((float*)C)[(size_t)(row + r) * N + col] = v;
      }
    }
  }
}

// ---------------- flash causal attention, work-balanced pair version ----------------
// Block handles q-tiles i and 31-i (64 rows each, 4 waves x 16 rows) with a SHARED
// k-sweep: each K/V tile staged once, consumed by both q-tiles -> every block does
// exactly 33 q*k tile-computes (perfect balance). Q pre-scaled by SM_SCALE upstream.
// launch_bounds(256,2): (256,3) capped VGPRs at 84 -> accumulator spill to scratch,
// 1.7 GB of HBM scratch traffic, 400us. Budget 256 regs; HW still fits 2-3 blocks/CU.
__global__ __launch_bounds__(256, 2) void flash_attn(const bf16* __restrict__ qkv,
                                                     const bf16* __restrict__ vt,
                                                     bf16* __restrict__ attn) {
  constexpr int S = 2048, TH = 6144, HH = 2048, D = 128;
  __shared__ bf16 Kl[64][140];     // row stride 280B == 6 words mod 32
  __shared__ bf16 Vl[128][76];     // row stride 152B == 6 words mod 32
  __shared__ bf16 Pl[4][16][76];   // scatter: lrow offset 24 words mod 32 -> 2-way
  const int t = threadIdx.x, lane = t & 63, w = t >> 6;
  const int lrow = lane >> 4, lcol = lane & 15;

  // XCD swizzle: 64 consecutive-swz blocks = 4 bh -> ~4MB K/V footprint per XCD L2
  int id = blockIdx.y * gridDim.x + blockIdx.x;  // 512 blocks
  id = (id & 7) * 64 + (id >> 3);
  const int i = id & 15, bh = id >> 4;
  const int b = bh >> 4, h = bh & 15;
  const int q0a = i * 64, q0b = (31 - i) * 64;

  const bf16* Qp = qkv + (size_t)b * S * TH + (size_t)h * D;
  const bf16* Kp = Qp + 2048;
  const bf16* Vp = vt + (size_t)bh * D * S;

  short8 aqA[4], aqB[4];
#pragma unroll
  for (int kc = 0; kc < 4; kc++) {
    aqA[kc] = *(const short8*)&Qp[(size_t)(q0a + w * 16 + lcol) * TH + kc * 32 + lrow * 8];
    aqB[kc] = *(const short8*)&Qp[(size_t)(q0b + w * 16 + lcol) * TH + kc * 32 + lrow * 8];
  }

  f32x4 oA[8], oB[8];
  float mxA[4], lsA[4], mxB[4], lsB[4];
#pragma unroll
  for (int nd = 0; nd < 8; nd++) { oA[nd] = (f32x4){0.f,0.f,0.f,0.f}; oB[nd] = (f32x4){0.f,0.f,0.f,0.f}; }
#pragma unroll
  for (int r = 0; r < 4; r++) { mxA[r] = -1e30f; lsA[r] = 0.f; mxB[r] = -1e30f; lsB[r] = 0.f; }

  auto step = [&](int q0, const short8* aq, f32x4* o, float* mx, float* ls, int k0) {
    f32x4 s[4];
#pragma unroll
    for (int n = 0; n < 4; n++) s[n] = (f32x4){0.f, 0.f, 0.f, 0.f};
#pragma unroll
    for (int n = 0; n < 4; n++) {
      short8 bk[4];
#pragma unroll
      for (int kc = 0; kc < 4; kc++)
        bk[kc] = *(const short8*)&Kl[n * 16 + lcol][kc * 32 + lrow * 8];
#pragma unroll
      for (int kc = 0; kc < 4; kc++)
        s[n] = __builtin_amdgcn_mfma_f32_16x16x32_bf16(aq[kc], bk[kc], s[n], 0, 0, 0);
    }
    if (k0 + 63 > q0 + w * 16) {  // only the diagonal tile needs masking
#pragma unroll
      for (int n = 0; n < 4; n++)
#pragma unroll
        for (int r = 0; r < 4; r++) {
          int qg = q0 + w * 16 + lrow * 4 + r;
          int kg = k0 + n * 16 + lcol;
          if (kg > qg) s[n][r] = -1e30f;
        }
    }
#pragma unroll
    for (int r = 0; r < 4; r++) {
      float rm = fmaxf(fmaxf(s[0][r], s[1][r]), fmaxf(s[2][r], s[3][r]));
      rm = fmaxf(rm, __shfl_xor(rm, 1));
      rm = fmaxf(rm, __shfl_xor(rm, 2));
      rm = fmaxf(rm, __shfl_xor(rm, 4));
      rm = fmaxf(rm, __shfl_xor(rm, 8));
      const float mn = fmaxf(mx[r], rm);
      const float fac = __expf(mx[r] - mn);
      mx[r] = mn;
      float rs = 0.f;
#pragma unroll
      for (int n = 0; n < 4; n++) {
        float p = __expf(s[n][r] - mn);
        s[n][r] = p;
        rs += p;
      }
      rs += __shfl_xor(rs, 1);
      rs += __shfl_xor(rs, 2);
      rs += __shfl_xor(rs, 4);
      rs += __shfl_xor(rs, 8);
      ls[r] = ls[r] * fac + rs;
#pragma unroll
      for (int nd = 0; nd < 8; nd++) o[nd][r] *= fac;
    }
    // P -> per-wave LDS (C-layout scatter), reload as A-fragments
#pragma unroll
    for (int n = 0; n < 4; n++)
#pragma unroll
      for (int r = 0; r < 4; r++)
        Pl[w][lrow * 4 + r][n * 16 + lcol] = __float2bfloat16(s[n][r]);
    short8 ap[2];
#pragma unroll
    for (int kc = 0; kc < 2; kc++)
      ap[kc] = *(const short8*)&Pl[w][lcol][kc * 32 + lrow * 8];
#pragma unroll
    for (int nd = 0; nd < 8; nd++) {
      short8 bv[2];
#pragma unroll
      for (int kc = 0; kc < 2; kc++)
        bv[kc] = *(const short8*)&Vl[nd * 16 + lcol][kc * 32 + lrow * 8];
#pragma unroll
      for (int kc = 0; kc < 2; kc++)
        o[nd] = __builtin_amdgcn_mfma_f32_16x16x32_bf16(ap[kc], bv[kc], o[nd], 0, 0, 0);
    }
  };

  const int nkt = 32 - i;  // k-tiles 0 .. 31-i  (tile B's full causal range)
  for (int kt = 0; kt < nkt; ++kt) {
    const int k0 = kt * 64;
    __syncthreads();
#pragma unroll
    for (int i2 = 0; i2 < 4; i2++) {  // stage K: 64 x 128
      int idx = (i2 * 256 + t) * 8;
      int r = idx >> 7, c = idx & 127;
      *(short8*)&Kl[r][c] = *(const short8*)&Kp[(size_t)(k0 + r) * TH + c];
    }
#pragma unroll
    for (int i2 = 0; i2 < 4; i2++) {  // stage V^T: 128 x 64
      int idx = (i2 * 256 + t) * 8;
      int r = idx >> 6, c = idx & 63;
      *(short8*)&Vl[r][c] = *(const short8*)&Vp[(size_t)r * S + k0 + c];
    }
    __syncthreads();
    step(q0b, aqB, oB, mxB, lsB, k0);      // long tile: every k-tile
    if (kt <= i) step(q0a, aqA, oA, mxA, lsA, k0);  // short tile: k <= diag
  }

#pragma unroll
  for (int nd = 0; nd < 8; nd++)
#pragma unroll
    for (int r = 0; r < 4; r++) {
      attn[(size_t)(b * S + q0a + w * 16 + lrow * 4 + r) * HH + h * D + nd * 16 + lcol] =
          __float2bfloat16(oA[nd][r] / lsA[r]);
      attn[(size_t)(b * S + q0b + w * 16 + lrow * 4 + r) * HH + h * D + nd * 16 + lcol] =
          __float2bfloat16(oB[nd][r] / lsB[r]);
    }
}

extern "C" void kernel_launch(void* const* d_in, const int* in_sizes, int n_in,
                              void* d_out, int out_size, void* d_ws, size_t ws_size,
                              hipStream_t stream) {
  const float* hidden = (const float*)d_in[0];  // [2,2048,2048]
  const float* w_attn = (const float*)d_in[1];  // [2048,6144]
  const float* b_attn = (const float*)d_in[2];  // [6144]
  const float* w_proj = (const float*)d_in[3];  // [2048,2048]
  const float* b_proj = (const float*)d_in[4];  // [2048]

  char* ws = (char*)d_ws;
  bf16* hb    = (bf16*)(ws);                 // [4096][2048]        16 MB
  bf16* wab_t = (bf16*)(ws + 16777216ull);   // [6144][2048]        24 MB
  bf16* wpb_t = (bf16*)(ws + 41943040ull);   // [2048][2048]         8 MB
  bf16* qkv   = (bf16*)(ws + 50331648ull);   // [4096][6144]        48 MB
  bf16* vt    = (bf16*)(ws + 100663296ull);  // [32][128][2048]     16 MB
  bf16* attn  = (bf16*)(ws + 117440512ull);  // [4096][2048]        16 MB  (total 128 MB)

  cvt_f32_bf16<<<4096, 256, 0, stream>>>(hidden, hb, 4096 * 2048 / 8);
  // fold softmax scale into W_q (cols < 2048 of w_attn)
  transpose_cvt<<<dim3(96, 32), 256, 0, stream>>>(w_attn, wab_t, 2048, 6144, 2048, SM_SCALE);
  transpose_cvt<<<dim3(32, 32), 256, 0, stream>>>(w_proj, wpb_t, 2048, 2048, 0, 1.f);
  gemm_bt<1><<<dim3(48, 32), 256, 0, stream>>>(hb, wab_t, b_attn, (void*)qkv, 4096, 6144, 2048,
                                               2048, SM_SCALE);
  build_vt<<<dim3(2, 32, 32), 256, 0, stream>>>(qkv, vt);
  flash_attn<<<dim3(16, 32), 256, 0, stream>>>(qkv, vt, attn);
  gemm_bt<0><<<dim3(16, 32), 256, 0, stream>>>(attn, wpb_t, b_proj, d_out, 4096, 2048, 2048,
                                               0, 1.f);
}

// Round 6
// 423.640 us; speedup vs baseline: 1.7273x; 1.1282x over previous
//
#include <hip/hip_runtime.h>
#include <hip/hip_bf16.h>
#include <stdint.h>

typedef __hip_bfloat16 bf16;
typedef __attribute__((ext_vector_type(4))) float f32x4;
typedef __attribute__((ext_vector_type(8))) short short8;

#define DEVI static __device__ __forceinline__
#define SM_SCALE 0.08838834764831845f

// async global->LDS, 16B per lane. LDS dest must be wave-uniform base; HW adds lane*16.
DEVI void gload_lds16(const bf16* g, bf16* l) {
  __builtin_amdgcn_global_load_lds(
      (const __attribute__((address_space(1))) unsigned int*)g,
      (__attribute__((address_space(3))) unsigned int*)l, 16, 0, 0);
}

// ---------------- fp32 -> bf16 elementwise convert (8 elems/thread) ----------------
__global__ __launch_bounds__(256) void cvt_f32_bf16(const float* __restrict__ in,
                                                    bf16* __restrict__ out, int n8) {
  int i = blockIdx.x * blockDim.x + threadIdx.x;
  if (i >= n8) return;
  const float4 a = *(const float4*)(in + (size_t)i * 8);
  const float4 b = *(const float4*)(in + (size_t)i * 8 + 4);
  bf16 t[8];
  t[0] = __float2bfloat16(a.x); t[1] = __float2bfloat16(a.y);
  t[2] = __float2bfloat16(a.z); t[3] = __float2bfloat16(a.w);
  t[4] = __float2bfloat16(b.x); t[5] = __float2bfloat16(b.y);
  t[6] = __float2bfloat16(b.z); t[7] = __float2bfloat16(b.w);
  *(short8*)(out + (size_t)i * 8) = *(const short8*)t;
}

// ---- fp32 [R][C] -> bf16 [C][R] transpose+convert; scales output-rows < scale_lt ----
__global__ __launch_bounds__(256) void transpose_cvt(const float* __restrict__ in,
                                                     bf16* __restrict__ out,
                                                     int R, int C, int scale_lt,
                                                     float scale) {
  __shared__ bf16 tile[64][72];
  const int c0 = blockIdx.x * 64, r0 = blockIdx.y * 64;
  const int t = threadIdx.x;
#pragma unroll
  for (int i = 0; i < 4; i++) {
    int idx = (i * 256 + t) * 4;
    int r = idx >> 6, c = idx & 63;
    float4 v = *(const float4*)&in[(size_t)(r0 + r) * C + c0 + c];
    float s0 = (c0 + c + 0 < scale_lt) ? scale : 1.f;
    float s1 = (c0 + c + 1 < scale_lt) ? scale : 1.f;
    float s2 = (c0 + c + 2 < scale_lt) ? scale : 1.f;
    float s3 = (c0 + c + 3 < scale_lt) ? scale : 1.f;
    tile[c + 0][r] = __float2bfloat16(v.x * s0);
    tile[c + 1][r] = __float2bfloat16(v.y * s1);
    tile[c + 2][r] = __float2bfloat16(v.z * s2);
    tile[c + 3][r] = __float2bfloat16(v.w * s3);
  }
  __syncthreads();
#pragma unroll
  for (int i = 0; i < 2; i++) {
    int idx = (i * 256 + t) * 8;
    int c = idx >> 6, r = idx & 63;
    *(short8*)&out[(size_t)(c0 + c) * R + r0 + r] = *(const short8*)&tile[c][r];
  }
}

// ------- extract V head-blocks from qkv and transpose: vt[bh][d=128][s=2048] -------
__global__ __launch_bounds__(256) void build_vt(const bf16* __restrict__ qkv,
                                                bf16* __restrict__ vt) {
  __shared__ bf16 tile[64][72];
  const int bh = blockIdx.z, b = bh >> 4, h = bh & 15;
  const bf16* src = qkv + (size_t)b * 2048 * 6144 + 4096 + (size_t)h * 128;
  bf16* dst = vt + (size_t)bh * 128 * 2048;
  const int s0 = blockIdx.y * 64, d0 = blockIdx.x * 64;
  const int t = threadIdx.x;
#pragma unroll
  for (int i = 0; i < 2; i++) {
    int idx = (i * 256 + t) * 8;
    int r = idx >> 6, c = idx & 63;
    short8 v = *(const short8*)&src[(size_t)(s0 + r) * 6144 + d0 + c];
    bf16* vv = (bf16*)&v;
#pragma unroll
    for (int j = 0; j < 8; j++) tile[c + j][r] = vv[j];
  }
  __syncthreads();
#pragma unroll
  for (int i = 0; i < 2; i++) {
    int idx = (i * 256 + t) * 8;
    int r = idx >> 6, c = idx & 63;
    *(short8*)&dst[(size_t)(d0 + r) * 2048 + s0 + c] = *(const short8*)&tile[r][c];
  }
}

// ---------------- m97-structure GEMM: C[M][N] = A[M][K] * Bt[N][K]^T + bias ----------------
// bias cols < bias_lt get multiplied by bscale (folds softmax scale into Q bias).
template <int OUT_BF16>
__global__ __launch_bounds__(256, 2) void gemm_bt(const bf16* __restrict__ A,
                                                  const bf16* __restrict__ Bt,
                                                  const float* __restrict__ bias,
                                                  void* __restrict__ C,
                                                  const int M, const int N, const int K,
                                                  const int bias_lt, const float bscale) {
  __shared__ bf16 As[128 * 32];
  __shared__ bf16 Bs[128 * 32];
  const int t = threadIdx.x, lane = t & 63, w = t >> 6;
  const int wr = w >> 1, wc = w & 1;
  const int lrow = lane >> 4, lcol = lane & 15;

  int bid = blockIdx.y * gridDim.x + blockIdx.x;
  const int nwg = gridDim.x * gridDim.y;
  bid = (bid & 7) * (nwg >> 3) + (bid >> 3);
  const int bx = bid % gridDim.x, by = bid / gridDim.x;
  const int m0 = by * 128, n0 = bx * 128;

  f32x4 acc[4][4];
#pragma unroll
  for (int i = 0; i < 4; i++)
#pragma unroll
    for (int j = 0; j < 4; j++) acc[i][j] = (f32x4){0.f, 0.f, 0.f, 0.f};

  for (int k0 = 0; k0 < K; k0 += 32) {
    __syncthreads();
#pragma unroll
    for (int i = 0; i < 2; i++) {
      const int o = i * 256 + t;
      gload_lds16(&A[(size_t)(m0 + (o >> 2)) * K + k0 + ((o & 3) << 3)],
                  &As[(i * 256 + w * 64) * 8]);
      gload_lds16(&Bt[(size_t)(n0 + (o >> 2)) * K + k0 + ((o & 3) << 3)],
                  &Bs[(i * 256 + w * 64) * 8]);
    }
    asm volatile("s_waitcnt vmcnt(0)" ::: "memory");
    __syncthreads();
    short8 af[4], bfr[4];
#pragma unroll
    for (int m = 0; m < 4; m++)
      af[m] = *(const short8*)&As[(wr * 64 + m * 16 + lcol) * 32 + lrow * 8];
#pragma unroll
    for (int n = 0; n < 4; n++)
      bfr[n] = *(const short8*)&Bs[(wc * 64 + n * 16 + lcol) * 32 + lrow * 8];
#pragma unroll
    for (int m = 0; m < 4; m++)
#pragma unroll
      for (int n = 0; n < 4; n++)
        acc[m][n] = __builtin_amdgcn_mfma_f32_16x16x32_bf16(af[m], bfr[n], acc[m][n], 0, 0, 0);
  }

  float bs[4];
#pragma unroll
  for (int n = 0; n < 4; n++) {
    const int col = n0 + wc * 64 + n * 16 + lcol;
    bs[n] = bias[col] * ((col < bias_lt) ? bscale : 1.f);
  }
#pragma unroll
  for (int m = 0; m < 4; m++) {
#pragma unroll
    for (int n = 0; n < 4; n++) {
      const int row = m0 + wr * 64 + m * 16 + lrow * 4;
      const int col = n0 + wc * 64 + n * 16 + lcol;
#pragma unroll
      for (int r = 0; r < 4; r++) {
        float v = acc[m][n][r] + bs[n];
        if (OUT_BF16)
          ((bf16*)C)[(size_t)(row + r) * N + col] = __float2bfloat16(v);
        else
          ((float*)C)[(size_t)(row + r) * N + col] = v;
      }
    }
  }
}

// ---------------- flash causal attention, work-balanced pair version ----------------
// Block handles q-tiles i and 31-i (64 rows each, 4 waves x 16 rows) with a SHARED
// k-sweep. FSTEP is a MACRO on named register arrays (rule #20: a lambda taking
// f32x4* pointers put the accumulators on the scratch stack -> 182 MB HBM writes).
// K/V for tile t+1 are prefetched into registers while tile t computes (T14).
#define FSTEP(q0v, aq, o, mx, ls)                                               \
  {                                                                             \
    f32x4 s[4];                                                                 \
    _Pragma("unroll") for (int n = 0; n < 4; n++) s[n] = (f32x4){0.f, 0.f, 0.f, 0.f}; \
    _Pragma("unroll") for (int n = 0; n < 4; n++) {                             \
      short8 bk[4];                                                             \
      _Pragma("unroll") for (int kc = 0; kc < 4; kc++)                          \
        bk[kc] = *(const short8*)&Kl[n * 16 + lcol][kc * 32 + lrow * 8];        \
      _Pragma("unroll") for (int kc = 0; kc < 4; kc++)                          \
        s[n] = __builtin_amdgcn_mfma_f32_16x16x32_bf16(aq[kc], bk[kc], s[n], 0, 0, 0); \
    }                                                                           \
    if (k0 + 63 > (q0v) + w * 16) {                                             \
      _Pragma("unroll") for (int n = 0; n < 4; n++)                             \
        _Pragma("unroll") for (int r = 0; r < 4; r++) {                         \
          int qg = (q0v) + w * 16 + lrow * 4 + r;                               \
          int kg = k0 + n * 16 + lcol;                                          \
          if (kg > qg) s[n][r] = -1e30f;                                        \
        }                                                                       \
    }                                                                           \
    _Pragma("unroll") for (int r = 0; r < 4; r++) {                             \
      float rm = fmaxf(fmaxf(s[0][r], s[1][r]), fmaxf(s[2][r], s[3][r]));       \
      rm = fmaxf(rm, __shfl_xor(rm, 1));                                        \
      rm = fmaxf(rm, __shfl_xor(rm, 2));                                        \
      rm = fmaxf(rm, __shfl_xor(rm, 4));                                        \
      rm = fmaxf(rm, __shfl_xor(rm, 8));                                        \
      const float mn = fmaxf(mx[r], rm);                                        \
      const float fac = __expf(mx[r] - mn);                                     \
      mx[r] = mn;                                                               \
      float rs = 0.f;                                                           \
      _Pragma("unroll") for (int n = 0; n < 4; n++) {                           \
        float p = __expf(s[n][r] - mn);                                         \
        s[n][r] = p;                                                            \
        rs += p;                                                                \
      }                                                                         \
      rs += __shfl_xor(rs, 1);                                                  \
      rs += __shfl_xor(rs, 2);                                                  \
      rs += __shfl_xor(rs, 4);                                                  \
      rs += __shfl_xor(rs, 8);                                                  \
      ls[r] = ls[r] * fac + rs;                                                 \
      _Pragma("unroll") for (int nd = 0; nd < 8; nd++) o[nd][r] *= fac;         \
    }                                                                           \
    _Pragma("unroll") for (int n = 0; n < 4; n++)                               \
      _Pragma("unroll") for (int r = 0; r < 4; r++)                             \
        Pl[w][lrow * 4 + r][n * 16 + lcol] = __float2bfloat16(s[n][r]);         \
    short8 ap[2];                                                               \
    _Pragma("unroll") for (int kc = 0; kc < 2; kc++)                            \
      ap[kc] = *(const short8*)&Pl[w][lcol][kc * 32 + lrow * 8];                \
    _Pragma("unroll") for (int nd = 0; nd < 8; nd++) {                          \
      short8 bv[2];                                                             \
      _Pragma("unroll") for (int kc = 0; kc < 2; kc++)                          \
        bv[kc] = *(const short8*)&Vl[nd * 16 + lcol][kc * 32 + lrow * 8];       \
      _Pragma("unroll") for (int kc = 0; kc < 2; kc++)                          \
        o[nd] = __builtin_amdgcn_mfma_f32_16x16x32_bf16(ap[kc], bv[kc], o[nd], 0, 0, 0); \
    }                                                                           \
  }

__global__ __launch_bounds__(256, 2) void flash_attn(const bf16* __restrict__ qkv,
                                                     const bf16* __restrict__ vt,
                                                     bf16* __restrict__ attn) {
  constexpr int S = 2048, TH = 6144, HH = 2048, D = 128;
  __shared__ bf16 Kl[64][140];     // row stride 280B == 6 words mod 32
  __shared__ bf16 Vl[128][76];     // row stride 152B == 6 words mod 32
  __shared__ bf16 Pl[4][16][76];
  const int t = threadIdx.x, lane = t & 63, w = t >> 6;
  const int lrow = lane >> 4, lcol = lane & 15;

  // XCD swizzle: 64 consecutive-swz blocks = 4 bh -> ~4MB K/V footprint per XCD L2
  int id = blockIdx.y * gridDim.x + blockIdx.x;  // 512 blocks
  id = (id & 7) * 64 + (id >> 3);
  const int i = id & 15, bh = id >> 4;
  const int b = bh >> 4, h = bh & 15;
  const int q0a = i * 64, q0b = (31 - i) * 64;

  const bf16* Qp = qkv + (size_t)b * S * TH + (size_t)h * D;
  const bf16* Kp = Qp + 2048;
  const bf16* Vp = vt + (size_t)bh * D * S;

  short8 aqA[4], aqB[4];
#pragma unroll
  for (int kc = 0; kc < 4; kc++) {
    aqA[kc] = *(const short8*)&Qp[(size_t)(q0a + w * 16 + lcol) * TH + kc * 32 + lrow * 8];
    aqB[kc] = *(const short8*)&Qp[(size_t)(q0b + w * 16 + lcol) * TH + kc * 32 + lrow * 8];
  }

  f32x4 oA[8], oB[8];
  float mxA[4], lsA[4], mxB[4], lsB[4];
#pragma unroll
  for (int nd = 0; nd < 8; nd++) { oA[nd] = (f32x4){0.f,0.f,0.f,0.f}; oB[nd] = (f32x4){0.f,0.f,0.f,0.f}; }
#pragma unroll
  for (int r = 0; r < 4; r++) { mxA[r] = -1e30f; lsA[r] = 0.f; mxB[r] = -1e30f; lsB[r] = 0.f; }

  // T14 staging registers + prologue loads for tile 0
  short8 kreg[4], vreg[4];
#pragma unroll
  for (int i2 = 0; i2 < 4; i2++) {
    int idx = (i2 * 256 + t) * 8;
    int r = idx >> 7, c = idx & 127;
    kreg[i2] = *(const short8*)&Kp[(size_t)r * TH + c];
    int rv = idx >> 6, cv = idx & 63;
    vreg[i2] = *(const short8*)&Vp[(size_t)rv * S + cv];
  }

  const int nkt = 32 - i;  // k-tiles 0 .. 31-i  (tile B's full causal range)
  for (int kt = 0; kt < nkt; ++kt) {
    const int k0 = kt * 64;
    __syncthreads();  // previous tile fully consumed; LDS writable
#pragma unroll
    for (int i2 = 0; i2 < 4; i2++) {
      int idx = (i2 * 256 + t) * 8;
      int r = idx >> 7, c = idx & 127;
      *(short8*)&Kl[r][c] = kreg[i2];
      int rv = idx >> 6, cv = idx & 63;
      *(short8*)&Vl[rv][cv] = vreg[i2];
    }
    if (kt + 1 < nkt) {  // prefetch next tile; latency hides under FSTEP compute
      const int k1 = k0 + 64;
#pragma unroll
      for (int i2 = 0; i2 < 4; i2++) {
        int idx = (i2 * 256 + t) * 8;
        int r = idx >> 7, c = idx & 127;
        kreg[i2] = *(const short8*)&Kp[(size_t)(k1 + r) * TH + c];
        int rv = idx >> 6, cv = idx & 63;
        vreg[i2] = *(const short8*)&Vp[(size_t)rv * S + k1 + cv];
      }
    }
    __syncthreads();
    FSTEP(q0b, aqB, oB, mxB, lsB);               // long tile: every k-tile
    if (kt <= i) FSTEP(q0a, aqA, oA, mxA, lsA);  // short tile: k <= diag
  }

#pragma unroll
  for (int nd = 0; nd < 8; nd++)
#pragma unroll
    for (int r = 0; r < 4; r++) {
      attn[(size_t)(b * S + q0a + w * 16 + lrow * 4 + r) * HH + h * D + nd * 16 + lcol] =
          __float2bfloat16(oA[nd][r] / lsA[r]);
      attn[(size_t)(b * S + q0b + w * 16 + lrow * 4 + r) * HH + h * D + nd * 16 + lcol] =
          __float2bfloat16(oB[nd][r] / lsB[r]);
    }
}

extern "C" void kernel_launch(void* const* d_in, const int* in_sizes, int n_in,
                              void* d_out, int out_size, void* d_ws, size_t ws_size,
                              hipStream_t stream) {
  const float* hidden = (const float*)d_in[0];  // [2,2048,2048]
  const float* w_attn = (const float*)d_in[1];  // [2048,6144]
  const float* b_attn = (const float*)d_in[2];  // [6144]
  const float* w_proj = (const float*)d_in[3];  // [2048,2048]
  const float* b_proj = (const float*)d_in[4];  // [2048]

  char* ws = (char*)d_ws;
  bf16* hb    = (bf16*)(ws);                 // [4096][2048]        16 MB
  bf16* wab_t = (bf16*)(ws + 16777216ull);   // [6144][2048]        24 MB
  bf16* wpb_t = (bf16*)(ws + 41943040ull);   // [2048][2048]         8 MB
  bf16* qkv   = (bf16*)(ws + 50331648ull);   // [4096][6144]        48 MB
  bf16* vt    = (bf16*)(ws + 100663296ull);  // [32][128][2048]     16 MB
  bf16* attn  = (bf16*)(ws + 117440512ull);  // [4096][2048]        16 MB  (total 128 MB)

  cvt_f32_bf16<<<4096, 256, 0, stream>>>(hidden, hb, 4096 * 2048 / 8);
  // fold softmax scale into W_q (cols < 2048 of w_attn)
  transpose_cvt<<<dim3(96, 32), 256, 0, stream>>>(w_attn, wab_t, 2048, 6144, 2048, SM_SCALE);
  transpose_cvt<<<dim3(32, 32), 256, 0, stream>>>(w_proj, wpb_t, 2048, 2048, 0, 1.f);
  gemm_bt<1><<<dim3(48, 32), 256, 0, stream>>>(hb, wab_t, b_attn, (void*)qkv, 4096, 6144, 2048,
                                               2048, SM_SCALE);
  build_vt<<<dim3(2, 32, 32), 256, 0, stream>>>(qkv, vt);
  flash_attn<<<dim3(16, 32), 256, 0, stream>>>(qkv, vt, attn);
  gemm_bt<0><<<dim3(16, 32), 256, 0, stream>>>(attn, wpb_t, b_proj, d_out, 4096, 2048, 2048,
                                               0, 1.f);
}

// Round 7
// 402.818 us; speedup vs baseline: 1.8166x; 1.0517x over previous
//
#include <hip/hip_runtime.h>
#include <hip/hip_bf16.h>
#include <stdint.h>

typedef __hip_bfloat16 bf16;
typedef __attribute__((ext_vector_type(4))) float f32x4;
typedef __attribute__((ext_vector_type(8))) short short8;

#define DEVI static __device__ __forceinline__
#define SM_SCALE 0.08838834764831845f

// async global->LDS, 16B per lane. LDS dest must be wave-uniform base; HW adds lane*16.
DEVI void gload_lds16(const bf16* g, bf16* l) {
  __builtin_amdgcn_global_load_lds(
      (const __attribute__((address_space(1))) unsigned int*)g,
      (__attribute__((address_space(3))) unsigned int*)l, 16, 0, 0);
}

// ---------------- fp32 -> bf16 elementwise convert (8 elems/thread) ----------------
__global__ __launch_bounds__(256) void cvt_f32_bf16(const float* __restrict__ in,
                                                    bf16* __restrict__ out, int n8) {
  int i = blockIdx.x * blockDim.x + threadIdx.x;
  if (i >= n8) return;
  const float4 a = *(const float4*)(in + (size_t)i * 8);
  const float4 b = *(const float4*)(in + (size_t)i * 8 + 4);
  bf16 t[8];
  t[0] = __float2bfloat16(a.x); t[1] = __float2bfloat16(a.y);
  t[2] = __float2bfloat16(a.z); t[3] = __float2bfloat16(a.w);
  t[4] = __float2bfloat16(b.x); t[5] = __float2bfloat16(b.y);
  t[6] = __float2bfloat16(b.z); t[7] = __float2bfloat16(b.w);
  *(short8*)(out + (size_t)i * 8) = *(const short8*)t;
}

// ---- fp32 [R][C] -> bf16 [C][R] transpose+convert; scales output-rows < scale_lt ----
__global__ __launch_bounds__(256) void transpose_cvt(const float* __restrict__ in,
                                                     bf16* __restrict__ out,
                                                     int R, int C, int scale_lt,
                                                     float scale) {
  __shared__ bf16 tile[64][72];
  const int c0 = blockIdx.x * 64, r0 = blockIdx.y * 64;
  const int t = threadIdx.x;
#pragma unroll
  for (int i = 0; i < 4; i++) {
    int idx = (i * 256 + t) * 4;
    int r = idx >> 6, c = idx & 63;
    float4 v = *(const float4*)&in[(size_t)(r0 + r) * C + c0 + c];
    float s0 = (c0 + c + 0 < scale_lt) ? scale : 1.f;
    float s1 = (c0 + c + 1 < scale_lt) ? scale : 1.f;
    float s2 = (c0 + c + 2 < scale_lt) ? scale : 1.f;
    float s3 = (c0 + c + 3 < scale_lt) ? scale : 1.f;
    tile[c + 0][r] = __float2bfloat16(v.x * s0);
    tile[c + 1][r] = __float2bfloat16(v.y * s1);
    tile[c + 2][r] = __float2bfloat16(v.z * s2);
    tile[c + 3][r] = __float2bfloat16(v.w * s3);
  }
  __syncthreads();
#pragma unroll
  for (int i = 0; i < 2; i++) {
    int idx = (i * 256 + t) * 8;
    int c = idx >> 6, r = idx & 63;
    *(short8*)&out[(size_t)(c0 + c) * R + r0 + r] = *(const short8*)&tile[c][r];
  }
}

// ------- extract V head-blocks from qkv and transpose: vt[bh][d=128][s=2048] -------
__global__ __launch_bounds__(256) void build_vt(const bf16* __restrict__ qkv,
                                                bf16* __restrict__ vt) {
  __shared__ bf16 tile[64][72];
  const int bh = blockIdx.z, b = bh >> 4, h = bh & 15;
  const bf16* src = qkv + (size_t)b * 2048 * 6144 + 4096 + (size_t)h * 128;
  bf16* dst = vt + (size_t)bh * 128 * 2048;
  const int s0 = blockIdx.y * 64, d0 = blockIdx.x * 64;
  const int t = threadIdx.x;
#pragma unroll
  for (int i = 0; i < 2; i++) {
    int idx = (i * 256 + t) * 8;
    int r = idx >> 6, c = idx & 63;
    short8 v = *(const short8*)&src[(size_t)(s0 + r) * 6144 + d0 + c];
    bf16* vv = (bf16*)&v;
#pragma unroll
    for (int j = 0; j < 8; j++) tile[c + j][r] = vv[j];
  }
  __syncthreads();
#pragma unroll
  for (int i = 0; i < 2; i++) {
    int idx = (i * 256 + t) * 8;
    int r = idx >> 6, c = idx & 63;
    *(short8*)&dst[(size_t)(d0 + r) * 2048 + s0 + c] = *(const short8*)&tile[r][c];
  }
}

// =============== pipelined 256x256 GEMM, BK=32, 4 LDS buffers, depth-3 =================
// C[M][N] = A[M][K] * Bt[N][K]^T + bias. 512 threads = 8 waves (2 Mx4 N), wave = 128x64.
// Per K-tile: vmcnt(counted) -> raw s_barrier -> 12 swizzled ds_read_b128 ->
// stage(t+3) via gload_lds (linear dest, pre-swizzled SOURCE) -> setprio(1) 32 MFMA.
// Never drains vmcnt to 0 in the main loop (T3+T4); XOR swizzle kills the 8-way
// fragment-read bank conflict (T2): byte ^= ((byte>>7)&7)<<4 (involution).
#define STAGE(tt)                                                              \
  {                                                                            \
    const int sbuf_ = (tt) & 3;                                                \
    bf16* ab_ = &smem[sbuf_ * 16384 + (w << 9)];                               \
    bf16* bb_ = &smem[sbuf_ * 16384 + 8192 + (w << 9)];                        \
    gload_lds16(&A[offA0 + (size_t)(tt) * 32], ab_);                           \
    gload_lds16(&A[offA1 + (size_t)(tt) * 32], ab_ + 4096);                    \
    gload_lds16(&Bt[offB0 + (size_t)(tt) * 32], bb_);                          \
    gload_lds16(&Bt[offB1 + (size_t)(tt) * 32], bb_ + 4096);                   \
  }

#define GTAIL(tt, NWAIT)                                                       \
  {                                                                            \
    asm volatile("s_waitcnt vmcnt(" #NWAIT ")" ::: "memory");                  \
    asm volatile("s_barrier" ::: "memory");                                    \
    const int bb = ((tt) & 3) * 16384;                                         \
    short8 af[8], bfv[4];                                                      \
    _Pragma("unroll") for (int m = 0; m < 8; m++)                              \
        af[m] = *(const short8*)&smem[bb + aoe[m]];                            \
    _Pragma("unroll") for (int n = 0; n < 4; n++)                              \
        bfv[n] = *(const short8*)&smem[bb + boe[n]];                           \
    __builtin_amdgcn_s_setprio(1);                                             \
    _Pragma("unroll") for (int m = 0; m < 8; m++)                              \
      _Pragma("unroll") for (int n = 0; n < 4; n++)                            \
        acc[m][n] = __builtin_amdgcn_mfma_f32_16x16x32_bf16(af[m], bfv[n],     \
                                                            acc[m][n], 0, 0, 0); \
    __builtin_amdgcn_s_setprio(0);                                             \
  }

template <int OUT_BF16>
__global__ __launch_bounds__(512, 2) void gemm256(const bf16* __restrict__ A,
                                                  const bf16* __restrict__ Bt,
                                                  const float* __restrict__ bias,
                                                  void* __restrict__ C,
                                                  const int M, const int N, const int K,
                                                  const int bias_lt, const float bscale) {
  __shared__ bf16 smem[65536];  // 4 buffers x (A 16KB | B 16KB) = 128 KiB
  const int t = threadIdx.x, lane = t & 63, w = t >> 6;
  const int wr = w >> 2, wc = w & 3;          // wave -> (M-half, N-quarter)
  const int lrow = lane >> 4, lcol = lane & 15;

  int bid = blockIdx.y * gridDim.x + blockIdx.x;
  const int nwg = gridDim.x * gridDim.y;
  bid = (bid & 7) * (nwg >> 3) + (bid >> 3);  // XCD swizzle (nwg % 8 == 0)
  const int bx = bid % gridDim.x, by = bid / gridDim.x;
  const int m0 = by * 256, n0 = bx * 256;

  // gload source pre-swizzle: LDS linear dest offset o (bytes in 16KB tile);
  // data belonging at logical swz(o) is fetched so swizzled READS see logical data.
  size_t offA0, offA1, offB0, offB1;
  {
    int o = (w << 10) + ((lane & 63) << 4);
    int l0 = o ^ (((o >> 7) & 7) << 4);
    int o1 = o + 8192;
    int l1 = o1 ^ (((o1 >> 7) & 7) << 4);
    offA0 = (size_t)(m0 + (l0 >> 6)) * K + ((l0 & 63) >> 1);
    offA1 = (size_t)(m0 + (l1 >> 6)) * K + ((l1 & 63) >> 1);
    offB0 = (size_t)(n0 + (l0 >> 6)) * K + ((l0 & 63) >> 1);
    offB1 = (size_t)(n0 + (l1 >> 6)) * K + ((l1 & 63) >> 1);
  }
  // swizzled ds-read element offsets (loop-invariant; add buffer base per tile)
  int aoe[8], boe[4];
#pragma unroll
  for (int m = 0; m < 8; m++) {
    int lb = ((wr * 128 + m * 16 + lcol) << 6) + (lrow << 4);
    lb ^= ((lb >> 7) & 7) << 4;
    aoe[m] = lb >> 1;
  }
#pragma unroll
  for (int n = 0; n < 4; n++) {
    int lb = ((wc * 64 + n * 16 + lcol) << 6) + (lrow << 4);
    lb ^= ((lb >> 7) & 7) << 4;
    boe[n] = 8192 + (lb >> 1);
  }

  f32x4 acc[8][4];
#pragma unroll
  for (int m = 0; m < 8; m++)
#pragma unroll
    for (int n = 0; n < 4; n++) acc[m][n] = (f32x4){0.f, 0.f, 0.f, 0.f};

  const int NT = K >> 5;  // BK=32
  STAGE(0); STAGE(1); STAGE(2);  // depth-3 prologue (12 loads in flight)

  for (int tt = 0; tt < NT - 3; ++tt) {
    asm volatile("s_waitcnt vmcnt(8)" ::: "memory");  // own tile-tt loads landed
    asm volatile("s_barrier" ::: "memory");           // collective; no waitcnt drain
    const int bb = (tt & 3) * 16384;
    short8 af[8], bfv[4];
#pragma unroll
    for (int m = 0; m < 8; m++) af[m] = *(const short8*)&smem[bb + aoe[m]];
#pragma unroll
    for (int n = 0; n < 4; n++) bfv[n] = *(const short8*)&smem[bb + boe[n]];
    STAGE(tt + 3);  // overwrites buf[(tt-1)&3]; safe: issued after barrier
    __builtin_amdgcn_s_setprio(1);
#pragma unroll
    for (int m = 0; m < 8; m++)
#pragma unroll
      for (int n = 0; n < 4; n++)
        acc[m][n] = __builtin_amdgcn_mfma_f32_16x16x32_bf16(af[m], bfv[n], acc[m][n], 0, 0, 0);
    __builtin_amdgcn_s_setprio(0);
  }
  GTAIL(NT - 3, 8);
  GTAIL(NT - 2, 4);
  GTAIL(NT - 1, 0);

  float bs[4];
#pragma unroll
  for (int n = 0; n < 4; n++) {
    const int col = n0 + wc * 64 + n * 16 + lcol;
    bs[n] = bias[col] * ((col < bias_lt) ? bscale : 1.f);
  }
#pragma unroll
  for (int m = 0; m < 8; m++) {
#pragma unroll
    for (int n = 0; n < 4; n++) {
      const int row = m0 + wr * 128 + m * 16 + lrow * 4;
      const int col = n0 + wc * 64 + n * 16 + lcol;
#pragma unroll
      for (int r = 0; r < 4; r++) {
        float v = acc[m][n][r] + bs[n];
        if (OUT_BF16)
          ((bf16*)C)[(size_t)(row + r) * N + col] = __float2bfloat16(v);
        else
          ((float*)C)[(size_t)(row + r) * N + col] = v;
      }
    }
  }
}

// ---------------- m97-structure GEMM (kept for proj: only 128 wgs at 256 tile) --------
template <int OUT_BF16>
__global__ __launch_bounds__(256, 2) void gemm_bt(const bf16* __restrict__ A,
                                                  const bf16* __restrict__ Bt,
                                                  const float* __restrict__ bias,
                                                  void* __restrict__ C,
                                                  const int M, const int N, const int K,
                                                  const int bias_lt, const float bscale) {
  __shared__ bf16 As[128 * 32];
  __shared__ bf16 Bs[128 * 32];
  const int t = threadIdx.x, lane = t & 63, w = t >> 6;
  const int wr = w >> 1, wc = w & 1;
  const int lrow = lane >> 4, lcol = lane & 15;

  int bid = blockIdx.y * gridDim.x + blockIdx.x;
  const int nwg = gridDim.x * gridDim.y;
  bid = (bid & 7) * (nwg >> 3) + (bid >> 3);
  const int bx = bid % gridDim.x, by = bid / gridDim.x;
  const int m0 = by * 128, n0 = bx * 128;

  f32x4 acc[4][4];
#pragma unroll
  for (int i = 0; i < 4; i++)
#pragma unroll
    for (int j = 0; j < 4; j++) acc[i][j] = (f32x4){0.f, 0.f, 0.f, 0.f};

  for (int k0 = 0; k0 < K; k0 += 32) {
    __syncthreads();
#pragma unroll
    for (int i = 0; i < 2; i++) {
      const int o = i * 256 + t;
      gload_lds16(&A[(size_t)(m0 + (o >> 2)) * K + k0 + ((o & 3) << 3)],
                  &As[(i * 256 + w * 64) * 8]);
      gload_lds16(&Bt[(size_t)(n0 + (o >> 2)) * K + k0 + ((o & 3) << 3)],
                  &Bs[(i * 256 + w * 64) * 8]);
    }
    asm volatile("s_waitcnt vmcnt(0)" ::: "memory");
    __syncthreads();
    short8 af[4], bfr[4];
#pragma unroll
    for (int m = 0; m < 4; m++)
      af[m] = *(const short8*)&As[(wr * 64 + m * 16 + lcol) * 32 + lrow * 8];
#pragma unroll
    for (int n = 0; n < 4; n++)
      bfr[n] = *(const short8*)&Bs[(wc * 64 + n * 16 + lcol) * 32 + lrow * 8];
#pragma unroll
    for (int m = 0; m < 4; m++)
#pragma unroll
      for (int n = 0; n < 4; n++)
        acc[m][n] = __builtin_amdgcn_mfma_f32_16x16x32_bf16(af[m], bfr[n], acc[m][n], 0, 0, 0);
  }

  float bs[4];
#pragma unroll
  for (int n = 0; n < 4; n++) {
    const int col = n0 + wc * 64 + n * 16 + lcol;
    bs[n] = bias[col] * ((col < bias_lt) ? bscale : 1.f);
  }
#pragma unroll
  for (int m = 0; m < 4; m++) {
#pragma unroll
    for (int n = 0; n < 4; n++) {
      const int row = m0 + wr * 64 + m * 16 + lrow * 4;
      const int col = n0 + wc * 64 + n * 16 + lcol;
#pragma unroll
      for (int r = 0; r < 4; r++) {
        float v = acc[m][n][r] + bs[n];
        if (OUT_BF16)
          ((bf16*)C)[(size_t)(row + r) * N + col] = __float2bfloat16(v);
        else
          ((float*)C)[(size_t)(row + r) * N + col] = v;
      }
    }
  }
}

// ---------------- flash causal attention, work-balanced pair version ----------------
// Block handles q-tiles i and 31-i (64 rows each, 4 waves x 16 rows) with a SHARED
// k-sweep. FSTEP is a MACRO on named register arrays (rule #20: a lambda taking
// f32x4* pointers put the accumulators on the scratch stack -> 182 MB HBM writes).
// K/V for tile t+1 are prefetched into registers while tile t computes (T14).
#define FSTEP(q0v, aq, o, mx, ls)                                               \
  {                                                                             \
    f32x4 s[4];                                                                 \
    _Pragma("unroll") for (int n = 0; n < 4; n++) s[n] = (f32x4){0.f, 0.f, 0.f, 0.f}; \
    _Pragma("unroll") for (int n = 0; n < 4; n++) {                             \
      short8 bk[4];                                                             \
      _Pragma("unroll") for (int kc = 0; kc < 4; kc++)                          \
        bk[kc] = *(const short8*)&Kl[n * 16 + lcol][kc * 32 + lrow * 8];        \
      _Pragma("unroll") for (int kc = 0; kc < 4; kc++)                          \
        s[n] = __builtin_amdgcn_mfma_f32_16x16x32_bf16(aq[kc], bk[kc], s[n], 0, 0, 0); \
    }                                                                           \
    if (k0 + 63 > (q0v) + w * 16) {                                             \
      _Pragma("unroll") for (int n = 0; n < 4; n++)                             \
        _Pragma("unroll") for (int r = 0; r < 4; r++) {                         \
          int qg = (q0v) + w * 16 + lrow * 4 + r;                               \
          int kg = k0 + n * 16 + lcol;                                          \
          if (kg > qg) s[n][r] = -1e30f;                                        \
        }                                                                       \
    }                                                                           \
    _Pragma("unroll") for (int r = 0; r < 4; r++) {                             \
      float rm = fmaxf(fmaxf(s[0][r], s[1][r]), fmaxf(s[2][r], s[3][r]));       \
      rm = fmaxf(rm, __shfl_xor(rm, 1));                                        \
      rm = fmaxf(rm, __shfl_xor(rm, 2));                                        \
      rm = fmaxf(rm, __shfl_xor(rm, 4));                                        \
      rm = fmaxf(rm, __shfl_xor(rm, 8));                                        \
      const float mn = fmaxf(mx[r], rm);                                        \
      const float fac = __expf(mx[r] - mn);                                     \
      mx[r] = mn;                                                               \
      float rs = 0.f;                                                           \
      _Pragma("unroll") for (int n = 0; n < 4; n++) {                           \
        float p = __expf(s[n][r] - mn);                                         \
        s[n][r] = p;                                                            \
        rs += p;                                                                \
      }                                                                         \
      rs += __shfl_xor(rs, 1);                                                  \
      rs += __shfl_xor(rs, 2);                                                  \
      rs += __shfl_xor(rs, 4);                                                  \
      rs += __shfl_xor(rs, 8);                                                  \
      ls[r] = ls[r] * fac + rs;                                                 \
      _Pragma("unroll") for (int nd = 0; nd < 8; nd++) o[nd][r] *= fac;         \
    }                                                                           \
    _Pragma("unroll") for (int n = 0; n < 4; n++)                               \
      _Pragma("unroll") for (int r = 0; r < 4; r++)                             \
        Pl[w][lrow * 4 + r][n * 16 + lcol] = __float2bfloat16(s[n][r]);         \
    short8 ap[2];                                                               \
    _Pragma("unroll") for (int kc = 0; kc < 2; kc++)                            \
      ap[kc] = *(const short8*)&Pl[w][lcol][kc * 32 + lrow * 8];                \
    _Pragma("unroll") for (int nd = 0; nd < 8; nd++) {                          \
      short8 bv[2];                                                             \
      _Pragma("unroll") for (int kc = 0; kc < 2; kc++)                          \
        bv[kc] = *(const short8*)&Vl[nd * 16 + lcol][kc * 32 + lrow * 8];       \
      _Pragma("unroll") for (int kc = 0; kc < 2; kc++)                          \
        o[nd] = __builtin_amdgcn_mfma_f32_16x16x32_bf16(ap[kc], bv[kc], o[nd], 0, 0, 0); \
    }                                                                           \
  }

__global__ __launch_bounds__(256, 2) void flash_attn(const bf16* __restrict__ qkv,
                                                     const bf16* __restrict__ vt,
                                                     bf16* __restrict__ attn) {
  constexpr int S = 2048, TH = 6144, HH = 2048, D = 128;
  __shared__ bf16 Kl[64][140];     // row stride 280B == 6 words mod 32
  __shared__ bf16 Vl[128][76];     // row stride 152B == 6 words mod 32
  __shared__ bf16 Pl[4][16][76];
  const int t = threadIdx.x, lane = t & 63, w = t >> 6;
  const int lrow = lane >> 4, lcol = lane & 15;

  // XCD swizzle: 64 consecutive-swz blocks = 4 bh -> ~4MB K/V footprint per XCD L2
  int id = blockIdx.y * gridDim.x + blockIdx.x;  // 512 blocks
  id = (id & 7) * 64 + (id >> 3);
  const int i = id & 15, bh = id >> 4;
  const int b = bh >> 4, h = bh & 15;
  const int q0a = i * 64, q0b = (31 - i) * 64;

  const bf16* Qp = qkv + (size_t)b * S * TH + (size_t)h * D;
  const bf16* Kp = Qp + 2048;
  const bf16* Vp = vt + (size_t)bh * D * S;

  short8 aqA[4], aqB[4];
#pragma unroll
  for (int kc = 0; kc < 4; kc++) {
    aqA[kc] = *(const short8*)&Qp[(size_t)(q0a + w * 16 + lcol) * TH + kc * 32 + lrow * 8];
    aqB[kc] = *(const short8*)&Qp[(size_t)(q0b + w * 16 + lcol) * TH + kc * 32 + lrow * 8];
  }

  f32x4 oA[8], oB[8];
  float mxA[4], lsA[4], mxB[4], lsB[4];
#pragma unroll
  for (int nd = 0; nd < 8; nd++) { oA[nd] = (f32x4){0.f,0.f,0.f,0.f}; oB[nd] = (f32x4){0.f,0.f,0.f,0.f}; }
#pragma unroll
  for (int r = 0; r < 4; r++) { mxA[r] = -1e30f; lsA[r] = 0.f; mxB[r] = -1e30f; lsB[r] = 0.f; }

  // T14 staging registers + prologue loads for tile 0
  short8 kreg[4], vreg[4];
#pragma unroll
  for (int i2 = 0; i2 < 4; i2++) {
    int idx = (i2 * 256 + t) * 8;
    int r = idx >> 7, c = idx & 127;
    kreg[i2] = *(const short8*)&Kp[(size_t)r * TH + c];
    int rv = idx >> 6, cv = idx & 63;
    vreg[i2] = *(const short8*)&Vp[(size_t)rv * S + cv];
  }

  const int nkt = 32 - i;  // k-tiles 0 .. 31-i  (tile B's full causal range)
  for (int kt = 0; kt < nkt; ++kt) {
    const int k0 = kt * 64;
    __syncthreads();  // previous tile fully consumed; LDS writable
#pragma unroll
    for (int i2 = 0; i2 < 4; i2++) {
      int idx = (i2 * 256 + t) * 8;
      int r = idx >> 7, c = idx & 127;
      *(short8*)&Kl[r][c] = kreg[i2];
      int rv = idx >> 6, cv = idx & 63;
      *(short8*)&Vl[rv][cv] = vreg[i2];
    }
    if (kt + 1 < nkt) {  // prefetch next tile; latency hides under FSTEP compute
      const int k1 = k0 + 64;
#pragma unroll
      for (int i2 = 0; i2 < 4; i2++) {
        int idx = (i2 * 256 + t) * 8;
        int r = idx >> 7, c = idx & 127;
        kreg[i2] = *(const short8*)&Kp[(size_t)(k1 + r) * TH + c];
        int rv = idx >> 6, cv = idx & 63;
        vreg[i2] = *(const short8*)&Vp[(size_t)rv * S + k1 + cv];
      }
    }
    __syncthreads();
    FSTEP(q0b, aqB, oB, mxB, lsB);               // long tile: every k-tile
    if (kt <= i) FSTEP(q0a, aqA, oA, mxA, lsA);  // short tile: k <= diag
  }

#pragma unroll
  for (int nd = 0; nd < 8; nd++)
#pragma unroll
    for (int r = 0; r < 4; r++) {
      attn[(size_t)(b * S + q0a + w * 16 + lrow * 4 + r) * HH + h * D + nd * 16 + lcol] =
          __float2bfloat16(oA[nd][r] / lsA[r]);
      attn[(size_t)(b * S + q0b + w * 16 + lrow * 4 + r) * HH + h * D + nd * 16 + lcol] =
          __float2bfloat16(oB[nd][r] / lsB[r]);
    }
}

extern "C" void kernel_launch(void* const* d_in, const int* in_sizes, int n_in,
                              void* d_out, int out_size, void* d_ws, size_t ws_size,
                              hipStream_t stream) {
  const float* hidden = (const float*)d_in[0];  // [2,2048,2048]
  const float* w_attn = (const float*)d_in[1];  // [2048,6144]
  const float* b_attn = (const float*)d_in[2];  // [6144]
  const float* w_proj = (const float*)d_in[3];  // [2048,2048]
  const float* b_proj = (const float*)d_in[4];  // [2048]

  char* ws = (char*)d_ws;
  bf16* hb    = (bf16*)(ws);                 // [4096][2048]        16 MB
  bf16* wab_t = (bf16*)(ws + 16777216ull);   // [6144][2048]        24 MB
  bf16* wpb_t = (bf16*)(ws + 41943040ull);   // [2048][2048]         8 MB
  bf16* qkv   = (bf16*)(ws + 50331648ull);   // [4096][6144]        48 MB
  bf16* vt    = (bf16*)(ws + 100663296ull);  // [32][128][2048]     16 MB
  bf16* attn  = (bf16*)(ws + 117440512ull);  // [4096][2048]        16 MB  (total 128 MB)

  cvt_f32_bf16<<<4096, 256, 0, stream>>>(hidden, hb, 4096 * 2048 / 8);
  // fold softmax scale into W_q (cols < 2048 of w_attn)
  transpose_cvt<<<dim3(96, 32), 256, 0, stream>>>(w_attn, wab_t, 2048, 6144, 2048, SM_SCALE);
  transpose_cvt<<<dim3(32, 32), 256, 0, stream>>>(w_proj, wpb_t, 2048, 2048, 0, 1.f);
  gemm256<1><<<dim3(24, 16), 512, 0, stream>>>(hb, wab_t, b_attn, (void*)qkv, 4096, 6144, 2048,
                                               2048, SM_SCALE);
  build_vt<<<dim3(2, 32, 32), 256, 0, stream>>>(qkv, vt);
  flash_attn<<<dim3(16, 32), 256, 0, stream>>>(qkv, vt, attn);
  gemm_bt<0><<<dim3(16, 32), 256, 0, stream>>>(attn, wpb_t, b_proj, d_out, 4096, 2048, 2048,
                                               0, 1.f);
}